// Round 14
// baseline (70.521 us; speedup 1.0000x reference)
//
#include <hip/hip_runtime.h>

#define NB 32
#define NS 2048
#define NH 1024
#define WIN 15   // exp(sc-lse-0.5*d^2): score-lse<=0 -> |d|>15 underflows to 0.0f (matches ref)

// ---------------- K1: v[b,h] = sum_d dec[b,d]*Wa[d,h]; zero denomD. (unchanged R12)
__global__ __launch_bounds__(256) void k1_v(const float* __restrict__ dec,
                                            const float* __restrict__ Wa,
                                            float* __restrict__ v,
                                            double* __restrict__ denomD) {
    __shared__ float4 red4[256];
    int blk = blockIdx.x;
    int b = blk & 31, ht = blk >> 5;   // ht 0..3
    int t = threadIdx.x;
    if (blk == 0 && t < NB) denomD[t] = 0.0;

    int ds = t >> 6, hl = t & 63;
    int h = ht * 256 + hl * 4;
    const float* decb = dec + b * NH + ds * 256;
    const float* wa   = Wa + (size_t)(ds * 256) * NH + h;

    float4 accA = {0.f, 0.f, 0.f, 0.f}, accB = {0.f, 0.f, 0.f, 0.f};
#pragma unroll 4
    for (int d = 0; d < 256; d += 2) {
        float sA = decb[d];
        float sB = decb[d + 1];
        float4 wA = *(const float4*)(wa + (size_t)d * NH);
        float4 wB = *(const float4*)(wa + (size_t)(d + 1) * NH);
        accA.x = fmaf(sA, wA.x, accA.x); accA.y = fmaf(sA, wA.y, accA.y);
        accA.z = fmaf(sA, wA.z, accA.z); accA.w = fmaf(sA, wA.w, accA.w);
        accB.x = fmaf(sB, wB.x, accB.x); accB.y = fmaf(sB, wB.y, accB.y);
        accB.z = fmaf(sB, wB.z, accB.z); accB.w = fmaf(sB, wB.w, accB.w);
    }
    float4 acc = {accA.x + accB.x, accA.y + accB.y, accA.z + accB.z, accA.w + accB.w};
    red4[t] = acc;
    __syncthreads();
    if (t < 64) {
        float4 r0 = red4[t], r1 = red4[t + 64], r2 = red4[t + 128], r3 = red4[t + 192];
        float4 r = {r0.x + r1.x + r2.x + r3.x, r0.y + r1.y + r2.y + r3.y,
                    r0.z + r1.z + r2.z + r3.z, r0.w + r1.w + r2.w + r3.w};
        *(float4*)(v + b * NH + ht * 256 + t * 4) = r;
    }
}

// async global->LDS DMA of one full 1024-float row: 4x 16B/lane chunks.
// dest = wave-uniform base + lane*16; src already includes lane*4 floats.
__device__ __forceinline__ void stage_row(const float* g, float* l) {
    __builtin_amdgcn_global_load_lds((const __attribute__((address_space(1))) void*)g,
                                     (__attribute__((address_space(3))) void*)l, 16, 0, 0);
    __builtin_amdgcn_global_load_lds((const __attribute__((address_space(1))) void*)(g + 256),
                                     (__attribute__((address_space(3))) void*)(l + 256), 16, 0, 0);
    __builtin_amdgcn_global_load_lds((const __attribute__((address_space(1))) void*)(g + 512),
                                     (__attribute__((address_space(3))) void*)(l + 512), 16, 0, 0);
    __builtin_amdgcn_global_load_lds((const __attribute__((address_space(1))) void*)(g + 768),
                                     (__attribute__((address_space(3))) void*)(l + 768), 16, 0, 0);
}

// ---------------- K2: scores = enc.v via wave-private double-buffered DMA staging.
// Wave w stages AND computes only rows [w*8, w*8+8) of its block: no cross-wave
// hazard, no in-loop barriers; counted vmcnt self-pacing; sched_barrier(0) at BOTH
// ends of each iteration (stage cannot hoist over previous compute's ds_reads).
// Reduction order per row is byte-identical to R12. 64 rows/block, 1024 blocks.
__global__ __launch_bounds__(512) void k2_scores(const float* __restrict__ enc,
                                                 const float* __restrict__ v,
                                                 float* __restrict__ scores,
                                                 double* __restrict__ denomD) {
    __shared__ float buf[8][2][NH];     // [wave][slot][row] = 64 KB
    __shared__ float rowsc[64];
    int t = threadIdx.x, w = t >> 6, lane = t & 63;
    int b = blockIdx.x >> 5;            // 32 blocks per b
    int wrow0 = (blockIdx.x << 6) + w * 8;      // this wave's first global row
    const float* g0 = enc + (size_t)wrow0 * NH + lane * 4;

    // v fragments from global (L2-hot); drain so vmcnt counts DMAs only
    const float4* vb = (const float4*)(v + b * NH);
    float4 vr0 = vb[lane], vr1 = vb[64 + lane], vr2 = vb[128 + lane], vr3 = vb[192 + lane];
    asm volatile("s_waitcnt vmcnt(0)" ::: "memory");

    stage_row(g0, &buf[w][0][0]);       // prologue: row 0 -> slot 0

    float* sl0 = &buf[w][0][0];
    float* sl1 = &buf[w][1][0];

    for (int i = 0; i < 8; ++i) {
        __builtin_amdgcn_sched_barrier(0);          // fence: stage can't hoist over prev compute
        if (i < 7) {
            stage_row(g0 + (size_t)(i + 1) * NH, (i & 1) ? sl0 : sl1);
            asm volatile("s_waitcnt vmcnt(4)" ::: "memory");   // row i landed; row i+1 in flight
        } else {
            asm volatile("s_waitcnt vmcnt(0)" ::: "memory");
        }
        __builtin_amdgcn_sched_barrier(0);          // fence: ds_reads can't hoist over waitcnt
        const float4* fb = (const float4*)((i & 1) ? sl1 : sl0);
        float4 x0 = fb[lane];
        float4 x1 = fb[64 + lane];
        float4 x2 = fb[128 + lane];
        float4 x3 = fb[192 + lane];
        float s = 0.f;
        s = fmaf(x0.x, vr0.x, s); s = fmaf(x0.y, vr0.y, s);
        s = fmaf(x0.z, vr0.z, s); s = fmaf(x0.w, vr0.w, s);
        s = fmaf(x1.x, vr1.x, s); s = fmaf(x1.y, vr1.y, s);
        s = fmaf(x1.z, vr1.z, s); s = fmaf(x1.w, vr1.w, s);
        s = fmaf(x2.x, vr2.x, s); s = fmaf(x2.y, vr2.y, s);
        s = fmaf(x2.z, vr2.z, s); s = fmaf(x2.w, vr2.w, s);
        s = fmaf(x3.x, vr3.x, s); s = fmaf(x3.y, vr3.y, s);
        s = fmaf(x3.z, vr3.z, s); s = fmaf(x3.w, vr3.w, s);
#pragma unroll
        for (int off = 32; off >= 1; off >>= 1) s += __shfl_xor(s, off, 64);
        if (lane == 0) { scores[wrow0 + i] = s; rowsc[w * 8 + i] = s; }
    }
    __syncthreads();
    if (t < 64) {                        // wave 0: 64 row-partials -> one f64 atomic
        double e = exp((double)rowsc[t]);
#pragma unroll
        for (int off = 32; off >= 1; off >>= 1) e += __shfl_xor(e, off, 64);
        if (t == 0) atomicAdd(&denomD[b], e);
    }
}

// ---------------- K3: attn + owner-chunk windowed ctx. (unchanged R12)
__global__ __launch_bounds__(256) void k3_out(const float* __restrict__ enc,
                                              const float* __restrict__ scores,
                                              const int* __restrict__ ts,
                                              const double* __restrict__ denomD,
                                              float* __restrict__ ctx,
                                              float* __restrict__ attn) {
    __shared__ float wv[32];
    int b = blockIdx.x >> 3;
    int c = blockIdx.x & 7;
    int t = threadIdx.x;

    float lse = (float)log(denomD[b]);
    int p = ts[b];
    float pf = (float)p;

    int s = c * 256 + t;
    float sc = scores[b * NS + s];
    float d = (float)s - pf;
    attn[(size_t)b * NS + s] = expf(sc - lse - 0.5f * d * d);

    if ((p >> 8) == c) {
        int w0 = max(0, p - WIN), w1 = min(NS - 1, p + WIN);
        const float* sb = scores + (size_t)b * NS;
        if (t < 32) {
            int r = w0 + t;
            float w = 0.f;
            if (r <= w1) {
                float dr = (float)r - pf;
                w = expf(sb[r] - lse - 0.5f * dr * dr);
            }
            wv[t] = w;
        }
        __syncthreads();
        const float* eb = enc + (size_t)b * NS * NH;
        float a0 = 0.f, a1 = 0.f, a2 = 0.f, a3 = 0.f;
#pragma unroll 8
        for (int r = 0; r < 32; ++r) {
            float w = wv[r];
            const float* er = eb + (size_t)min(w0 + r, NS - 1) * NH;
            a0 = fmaf(w, er[t],       a0);
            a1 = fmaf(w, er[t + 256], a1);
            a2 = fmaf(w, er[t + 512], a2);
            a3 = fmaf(w, er[t + 768], a3);
        }
        ctx[b * NH + t]       = a0;
        ctx[b * NH + t + 256] = a1;
        ctx[b * NH + t + 512] = a2;
        ctx[b * NH + t + 768] = a3;
    }
}

extern "C" void kernel_launch(void* const* d_in, const int* in_sizes, int n_in,
                              void* d_out, int out_size, void* d_ws, size_t ws_size,
                              hipStream_t stream) {
    const float* enc  = (const float*)d_in[0];   // [B,S,H]
    const float* dec  = (const float*)d_in[1];   // [B,H]
    const int*   ts   = (const int*)d_in[2];     // [B]
    const float* Wa_w = (const float*)d_in[3];   // [H,H]
    // d_in[4] = Wa_b: uniform per-b score shift -> softmax-invariant, dropped.

    float* out  = (float*)d_out;
    float* ctx  = out;             // [B,H]
    float* attn = out + NB * NH;   // [B,S]

    float*  v      = (float*)d_ws;                  // NB*NH floats
    float*  scores = v + NB * NH;                   // NB*NS floats
    double* denomD = (double*)(scores + NB * NS);   // NB doubles (8B-aligned)

    k1_v     <<<128,  256, 0, stream>>>(dec, Wa_w, v, denomD);
    k2_scores<<<1024, 512, 0, stream>>>(enc, v, scores, denomD);
    k3_out   <<<NB*8, 256, 0, stream>>>(enc, scores, ts, denomD, ctx, attn);
}

// Round 15
// 66.802 us; speedup vs baseline: 1.0557x; 1.0557x over previous
//
#include <hip/hip_runtime.h>

#define NB 32
#define NS 2048
#define NH 1024
#define WIN 15   // exp(sc-lse-0.5*d^2): score-lse<=0 -> |d|>15 underflows to 0.0f (matches ref)

// ---------------- K1: v[b,h] = sum_d dec[b,d]*Wa[d,h]; zero denomD.
// float4-over-h: wave-load = 1KB coalesced. grid = 4 ht * 32 b.
__global__ __launch_bounds__(256) void k1_v(const float* __restrict__ dec,
                                            const float* __restrict__ Wa,
                                            float* __restrict__ v,
                                            double* __restrict__ denomD) {
    __shared__ float4 red4[256];
    int blk = blockIdx.x;
    int b = blk & 31, ht = blk >> 5;   // ht 0..3
    int t = threadIdx.x;
    if (blk == 0 && t < NB) denomD[t] = 0.0;

    int ds = t >> 6, hl = t & 63;      // ds = wave id (d-slice), hl = lane
    int h = ht * 256 + hl * 4;
    const float* decb = dec + b * NH + ds * 256;
    const float* wa   = Wa + (size_t)(ds * 256) * NH + h;

    float4 accA = {0.f, 0.f, 0.f, 0.f}, accB = {0.f, 0.f, 0.f, 0.f};
#pragma unroll 4
    for (int d = 0; d < 256; d += 2) {   // 2 split float4 accumulators
        float sA = decb[d];              // wave-uniform -> s_load
        float sB = decb[d + 1];
        float4 wA = *(const float4*)(wa + (size_t)d * NH);
        float4 wB = *(const float4*)(wa + (size_t)(d + 1) * NH);
        accA.x = fmaf(sA, wA.x, accA.x); accA.y = fmaf(sA, wA.y, accA.y);
        accA.z = fmaf(sA, wA.z, accA.z); accA.w = fmaf(sA, wA.w, accA.w);
        accB.x = fmaf(sB, wB.x, accB.x); accB.y = fmaf(sB, wB.y, accB.y);
        accB.z = fmaf(sB, wB.z, accB.z); accB.w = fmaf(sB, wB.w, accB.w);
    }
    float4 acc = {accA.x + accB.x, accA.y + accB.y, accA.z + accB.z, accA.w + accB.w};
    red4[t] = acc;
    __syncthreads();
    if (t < 64) {
        float4 r0 = red4[t], r1 = red4[t + 64], r2 = red4[t + 128], r3 = red4[t + 192];
        float4 r = {r0.x + r1.x + r2.x + r3.x, r0.y + r1.y + r2.y + r3.y,
                    r0.z + r1.z + r2.z + r3.z, r0.w + r1.w + r2.w + r3.w};
        *(float4*)(v + b * NH + ht * 256 + t * 4) = r;
    }
}

// ---------------- K2: scores[b,s] = enc[b,s,:].v[b,:]; per-block f64 denom atomic.
// 64 rows/block, 512 thr, 1024 blocks, 4 rows/wave, LDS-staged v -> 16 regs,
// row-serial compiler-scheduled loads, one atomic/block. (best of 6 variants)
__global__ __launch_bounds__(512) void k2_scores(const float* __restrict__ enc,
                                                 const float* __restrict__ v,
                                                 float* __restrict__ scores,
                                                 double* __restrict__ denomD) {
    __shared__ float vs[NH];
    __shared__ float rowsc[64];
    int t = threadIdx.x, wid = t >> 6, lane = t & 63;
    int b = blockIdx.x >> 5;           // 32 blocks per b
    int row0 = blockIdx.x << 6;        // 64 global rows per block

    ((float2*)vs)[t] = ((const float2*)(v + b * NH))[t];   // all 512 threads stage
    __syncthreads();
    const float4* vv = (const float4*)vs;
    float4 vr0 = vv[lane], vr1 = vv[64 + lane], vr2 = vv[128 + lane], vr3 = vv[192 + lane];

#pragma unroll
    for (int tile = 0; tile < 2; ++tile) {
        int r0 = row0 + tile * 32 + wid * 4;
        const float4* eb = (const float4*)(enc + (size_t)r0 * NH);
        float acc[4];
#pragma unroll
        for (int r = 0; r < 4; ++r) {
            float4 x0 = eb[r * 256 + lane];
            float4 x1 = eb[r * 256 + 64 + lane];
            float4 x2 = eb[r * 256 + 128 + lane];
            float4 x3 = eb[r * 256 + 192 + lane];
            float s = 0.f;
            s = fmaf(x0.x, vr0.x, s); s = fmaf(x0.y, vr0.y, s);
            s = fmaf(x0.z, vr0.z, s); s = fmaf(x0.w, vr0.w, s);
            s = fmaf(x1.x, vr1.x, s); s = fmaf(x1.y, vr1.y, s);
            s = fmaf(x1.z, vr1.z, s); s = fmaf(x1.w, vr1.w, s);
            s = fmaf(x2.x, vr2.x, s); s = fmaf(x2.y, vr2.y, s);
            s = fmaf(x2.z, vr2.z, s); s = fmaf(x2.w, vr2.w, s);
            s = fmaf(x3.x, vr3.x, s); s = fmaf(x3.y, vr3.y, s);
            s = fmaf(x3.z, vr3.z, s); s = fmaf(x3.w, vr3.w, s);
            acc[r] = s;
        }
#pragma unroll
        for (int r = 0; r < 4; ++r) {
#pragma unroll
            for (int off = 32; off >= 1; off >>= 1) acc[r] += __shfl_xor(acc[r], off, 64);
            if (lane == 0) {
                scores[r0 + r] = acc[r];
                rowsc[tile * 32 + wid * 4 + r] = acc[r];
            }
        }
    }
    __syncthreads();
    if (t < 64) {                       // wave 0: 64 row-partials -> one f64 atomic
        double e = exp((double)rowsc[t]);
#pragma unroll
        for (int off = 32; off >= 1; off >>= 1) e += __shfl_xor(e, off, 64);
        if (t == 0) atomicAdd(&denomD[b], e);
    }
}

// ---------------- K3: attn = exp(score - lse - 0.5 d^2); owner-chunk computes whole
// ctx window. Window loop is COMPILE-TIME 32 iterations (wv zero-padded, row index
// clamped) so loads pipeline instead of serializing. grid = 32 b * 8 s-chunks.
__global__ __launch_bounds__(256) void k3_out(const float* __restrict__ enc,
                                              const float* __restrict__ scores,
                                              const int* __restrict__ ts,
                                              const double* __restrict__ denomD,
                                              float* __restrict__ ctx,
                                              float* __restrict__ attn) {
    __shared__ float wv[32];
    int b = blockIdx.x >> 3;
    int c = blockIdx.x & 7;
    int t = threadIdx.x;

    float lse = (float)log(denomD[b]);
    int p = ts[b];
    float pf = (float)p;

    int s = c * 256 + t;
    float sc = scores[b * NS + s];
    float d = (float)s - pf;
    attn[(size_t)b * NS + s] = expf(sc - lse - 0.5f * d * d);

    if ((p >> 8) == c) {               // owner chunk (block-uniform): full window
        int w0 = max(0, p - WIN), w1 = min(NS - 1, p + WIN);
        const float* sb = scores + (size_t)b * NS;
        if (t < 32) {                  // zero-padded weights: exact (0 * x == 0)
            int r = w0 + t;
            float w = 0.f;
            if (r <= w1) {
                float dr = (float)r - pf;
                w = expf(sb[r] - lse - 0.5f * dr * dr);
            }
            wv[t] = w;
        }
        __syncthreads();
        const float* eb = enc + (size_t)b * NS * NH;
        float a0 = 0.f, a1 = 0.f, a2 = 0.f, a3 = 0.f;
#pragma unroll 8
        for (int r = 0; r < 32; ++r) {   // fixed bound -> pipelined loads
            float w = wv[r];
            const float* er = eb + (size_t)min(w0 + r, NS - 1) * NH;
            a0 = fmaf(w, er[t],       a0);
            a1 = fmaf(w, er[t + 256], a1);
            a2 = fmaf(w, er[t + 512], a2);
            a3 = fmaf(w, er[t + 768], a3);
        }
        ctx[b * NH + t]       = a0;
        ctx[b * NH + t + 256] = a1;
        ctx[b * NH + t + 512] = a2;
        ctx[b * NH + t + 768] = a3;
    }
}

extern "C" void kernel_launch(void* const* d_in, const int* in_sizes, int n_in,
                              void* d_out, int out_size, void* d_ws, size_t ws_size,
                              hipStream_t stream) {
    const float* enc  = (const float*)d_in[0];   // [B,S,H]
    const float* dec  = (const float*)d_in[1];   // [B,H]
    const int*   ts   = (const int*)d_in[2];     // [B]
    const float* Wa_w = (const float*)d_in[3];   // [H,H]
    // d_in[4] = Wa_b: uniform per-b score shift -> softmax-invariant, dropped.

    float* out  = (float*)d_out;
    float* ctx  = out;             // [B,H]
    float* attn = out + NB * NH;   // [B,S]

    float*  v      = (float*)d_ws;                  // NB*NH floats
    float*  scores = v + NB * NH;                   // NB*NS floats
    double* denomD = (double*)(scores + NB * NS);   // NB doubles (8B-aligned)

    k1_v     <<<128,  256, 0, stream>>>(dec, Wa_w, v, denomD);
    k2_scores<<<1024, 512, 0, stream>>>(enc, v, scores, denomD);
    k3_out   <<<NB*8, 256, 0, stream>>>(enc, scores, ts, denomD, ctx, attn);
}